// Round 2
// baseline (104.629 us; speedup 1.0000x reference)
//
#include <hip/hip_runtime.h>

constexpr int NB    = 64;    // batches
constexpr int NI    = 512;   // items per batch
constexpr int STK   = 6000;
constexpr int TILE_I = 64;   // i-values per block
constexpr int THREADS = 256; // 4 waves
constexpr int ROWP  = 20;    // padded row stride (floats): 80B, 16B-aligned, conflict-free

__global__ __launch_bounds__(THREADS)
void stock_factor_kernel(const float* __restrict__ prices,
                         const float* __restrict__ emb_table,
                         const float* __restrict__ beta,
                         const int* __restrict__ stock_ids,
                         float* __restrict__ out)
{
    __shared__ float semb[NI][ROWP];
    __shared__ int   ssid[NI];

    const int b    = blockIdx.x;
    const int tile = blockIdx.y;
    const int tid  = threadIdx.x;
    const int lane = tid & 63;
    const int wave = tid >> 6;

    // Stage: all 512 embeddings of this batch + their ids into LDS.
    for (int r = tid; r < NI; r += THREADS) {
        const int sid = stock_ids[b * NI + r];
        ssid[r] = sid;
        const float4* src = (const float4*)(emb_table + (long long)sid * 16);
        float4 v0 = src[0], v1 = src[1], v2 = src[2], v3 = src[3];
        float4* dst = (float4*)(&semb[r][0]);
        dst[0] = v0; dst[1] = v1; dst[2] = v2; dst[3] = v3;
    }
    __syncthreads();

    // Each wave owns 16 consecutive i's; lanes sweep j = lane + 64k.
    const int i0 = tile * TILE_I + wave * (TILE_I / 4);
    for (int ii = 0; ii < TILE_I / 4; ++ii) {
        const int i = i0 + ii;
        const int sid_i = ssid[i];
        const float* __restrict__ brow = beta + (long long)sid_i * STK;

        float ei[16];
        #pragma unroll
        for (int q = 0; q < 4; ++q) {
            float4 v = ((const float4*)(&semb[i][0]))[q];
            ei[4*q+0] = v.x; ei[4*q+1] = v.y; ei[4*q+2] = v.z; ei[4*q+3] = v.w;
        }

        float denom = 0.f, numer = 0.f;
        #pragma unroll
        for (int k = 0; k < 8; ++k) {
            const int j = lane + 64 * k;
            const float4* ej4 = (const float4*)(&semb[j][0]);
            const float4 a0 = ej4[0], a1 = ej4[1], a2 = ej4[2], a3 = ej4[3];

            const int   sid_j = ssid[j];
            const float bv    = brow[sid_j];     // the gather (wave-uniform row)

            float d;
            d  = ei[0]  * a0.x; d += ei[1]  * a0.y; d += ei[2]  * a0.z; d += ei[3]  * a0.w;
            d += ei[4]  * a1.x; d += ei[5]  * a1.y; d += ei[6]  * a1.z; d += ei[7]  * a1.w;
            d += ei[8]  * a2.x; d += ei[9]  * a2.y; d += ei[10] * a2.z; d += ei[11] * a2.w;
            d += ei[12] * a3.x; d += ei[13] * a3.y; d += ei[14] * a3.z; d += ei[15] * a3.w;

            float ex = expf(d);
            if (j == i) ex = 0.f;                       // diag: exp(-inf) = 0
            denom += ex;
            numer += (sid_j == sid_i) ? 0.f : ex * bv;  // beta zeroed on id match
        }

        // Wave-wide reduction of (denom, numer).
        #pragma unroll
        for (int off = 32; off; off >>= 1) {
            denom += __shfl_xor(denom, off);
            numer += __shfl_xor(numer, off);
        }

        if (lane == 0) {
            const float p = prices[b * NI + i];
            const float v = p * numer / (denom + 1e-8f);
            out[b * NI + i] = v;                  // virtual
            out[NB * NI + b * NI + i] = v - p;    // u
        }
    }
}

extern "C" void kernel_launch(void* const* d_in, const int* in_sizes, int n_in,
                              void* d_out, int out_size, void* d_ws, size_t ws_size,
                              hipStream_t stream) {
    const float* prices     = (const float*)d_in[0];
    const float* emb_table  = (const float*)d_in[1];
    const float* beta       = (const float*)d_in[2];
    const int*   stock_ids  = (const int*)d_in[3];
    float* out = (float*)d_out;

    dim3 grid(NB, NI / TILE_I);
    stock_factor_kernel<<<grid, THREADS, 0, stream>>>(prices, emb_table, beta,
                                                      stock_ids, out);
}